// Round 1
// baseline (3024.949 us; speedup 1.0000x reference)
//
#include <hip/hip_runtime.h>

#define N2 2048
#define DDIM 256
#define KNN 10
#define NCOL 512
#define FI 0.9090909090909091f
#define ABC (1.0f/2048.0f)
#define NIT_SINK 100
#define NIT_CHEB 32
#define BIGF 1e30f

// ---------------- exp + transpose: K = exp(-20*C), KT = K^T ----------------
__global__ __launch_bounds__(256) void k_exp_tr(const float* __restrict__ C,
                                                float* __restrict__ K,
                                                float* __restrict__ KT) {
  __shared__ float tile[32][33];
  int lane = threadIdx.x & 31, w8 = threadIdx.x >> 5;
  int gx = blockIdx.x * 32, gy = blockIdx.y * 32;
#pragma unroll
  for (int p = 0; p < 4; p++) {
    int row = gy + w8 + p * 8, col = gx + lane;
    float e = expf(-20.0f * C[(size_t)row * N2 + col]);
    K[(size_t)row * N2 + col] = e;
    tile[w8 + p * 8][lane] = e;
  }
  __syncthreads();
#pragma unroll
  for (int p = 0; p < 4; p++) {
    int row = gx + w8 + p * 8, col = gy + lane;
    KT[(size_t)row * N2 + col] = tile[lane][w8 + p * 8];
  }
}

__global__ void k_init(float* u, float* v, int* mdeg) {
  int t = blockIdx.x * 256 + threadIdx.x;
  if (t < N2) { u[t] = 1.0f; v[t] = 1.0f; }
  if (t < 2) mdeg[t] = 0;
}

// ---------------- Sinkhorn half-step: out = (a/(M@vin + eps))^fi -----------
// one wave (64 lanes) per row; 512 blocks x 256 threads = 2048 waves
__global__ __launch_bounds__(256) void k_sink(const float* __restrict__ M,
                                              const float* __restrict__ vin,
                                              float* __restrict__ out) {
  int w = blockIdx.x * 4 + (threadIdx.x >> 6);
  int lane = threadIdx.x & 63;
  const float4* Mr = (const float4*)(M + (size_t)w * N2);
  const float4* V = (const float4*)vin;
  float s = 0.0f;
#pragma unroll
  for (int q = 0; q < 8; q++) {
    float4 m4 = Mr[lane + 64 * q];
    float4 v4 = V[lane + 64 * q];
    s += m4.x * v4.x + m4.y * v4.y + m4.z * v4.z + m4.w * v4.w;
  }
#pragma unroll
  for (int off = 32; off; off >>= 1) s += __shfl_down(s, off);
  if (lane == 0) out[w] = powf(ABC / (s + 1e-16f), FI);
}

// scale[i] = w[i] / (w[i]*(M@vin)[i] + 1e-16)   (P marginal normalizer)
__global__ __launch_bounds__(256) void k_scale(const float* __restrict__ M,
                                               const float* __restrict__ vin,
                                               const float* __restrict__ wv,
                                               float* __restrict__ out) {
  int w = blockIdx.x * 4 + (threadIdx.x >> 6);
  int lane = threadIdx.x & 63;
  const float4* Mr = (const float4*)(M + (size_t)w * N2);
  const float4* V = (const float4*)vin;
  float s = 0.0f;
#pragma unroll
  for (int q = 0; q < 8; q++) {
    float4 m4 = Mr[lane + 64 * q];
    float4 v4 = V[lane + 64 * q];
    s += m4.x * v4.x + m4.y * v4.y + m4.z * v4.z + m4.w * v4.w;
  }
#pragma unroll
  for (int off = 32; off; off >>= 1) s += __shfl_down(s, off);
  if (lane == 0) out[w] = wv[w] / (wv[w] * s + 1e-16f);
}

// ---------------- sq norms: sq[i] = sum_d z[i][d]^2 ------------------------
__global__ __launch_bounds__(256) void k_sq(const float* __restrict__ z,
                                            float* __restrict__ sq) {
  int w = blockIdx.x * 4 + (threadIdx.x >> 6);
  int lane = threadIdx.x & 63;
  float4 z4 = ((const float4*)(z + (size_t)w * DDIM))[lane];
  float s = z4.x * z4.x + z4.y * z4.y + z4.z * z4.z + z4.w * z4.w;
#pragma unroll
  for (int off = 32; off; off >>= 1) s += __shfl_down(s, off);
  if (lane == 0) sq[w] = s;
}

// ---------------- fp32 tiled GEMM: C = A @ B (opt bscale/rscale) -----------
// BM=BN=64, BK=16, 256 threads, 4x4 per thread.
// TRANSB=0: B row-major [Kdim][ldb];  TRANSB=1: B[k][n] = Bz[n*ldb + k]
// SCALES=1: B[k][n] *= bscale[k], out row i *= rscale[i]
template <int TRANSB, int SCALES>
__global__ __launch_bounds__(256) void k_gemm(const float* __restrict__ A, int lda,
                                              const float* __restrict__ B, int ldb,
                                              const float* __restrict__ bscale,
                                              const float* __restrict__ rscale,
                                              float* __restrict__ C, int ldc,
                                              int ccol0, int Kdim) {
  __shared__ float AsT[16][68];
  __shared__ float Bs[16][68];
  int m0 = blockIdx.y * 64, n0 = blockIdx.x * 64;
  int tid = threadIdx.x;
  int tr = tid >> 4, tc = tid & 15;
  int ar = tid >> 2, aq = tid & 3;
  int br = tid >> 4, bq = tid & 15;
  float acc[4][4] = {};
  for (int k0 = 0; k0 < Kdim; k0 += 16) {
    float4 a4 = *(const float4*)(A + (size_t)(m0 + ar) * lda + k0 + aq * 4);
    AsT[aq * 4 + 0][ar] = a4.x;
    AsT[aq * 4 + 1][ar] = a4.y;
    AsT[aq * 4 + 2][ar] = a4.z;
    AsT[aq * 4 + 3][ar] = a4.w;
    if (TRANSB) {
      float4 b4 = *(const float4*)(B + (size_t)(n0 + ar) * ldb + k0 + aq * 4);
      Bs[aq * 4 + 0][ar] = b4.x;
      Bs[aq * 4 + 1][ar] = b4.y;
      Bs[aq * 4 + 2][ar] = b4.z;
      Bs[aq * 4 + 3][ar] = b4.w;
    } else {
      float4 b4 = *(const float4*)(B + (size_t)(k0 + br) * ldb + n0 + bq * 4);
      if (SCALES) {
        float sc = bscale[k0 + br];
        b4.x *= sc; b4.y *= sc; b4.z *= sc; b4.w *= sc;
      }
      *(float4*)&Bs[br][bq * 4] = b4;
    }
    __syncthreads();
#pragma unroll
    for (int kk = 0; kk < 16; kk++) {
      float4 av = *(const float4*)&AsT[kk][tr * 4];
      float4 bv = *(const float4*)&Bs[kk][tc * 4];
      acc[0][0] += av.x * bv.x; acc[0][1] += av.x * bv.y; acc[0][2] += av.x * bv.z; acc[0][3] += av.x * bv.w;
      acc[1][0] += av.y * bv.x; acc[1][1] += av.y * bv.y; acc[1][2] += av.y * bv.z; acc[1][3] += av.y * bv.w;
      acc[2][0] += av.z * bv.x; acc[2][1] += av.z * bv.y; acc[2][2] += av.z * bv.z; acc[2][3] += av.z * bv.w;
      acc[3][0] += av.w * bv.x; acc[3][1] += av.w * bv.y; acc[3][2] += av.w * bv.z; acc[3][3] += av.w * bv.w;
    }
    __syncthreads();
  }
#pragma unroll
  for (int i2 = 0; i2 < 4; i2++) {
    int row = m0 + tr * 4 + i2;
    float rs = SCALES ? rscale[row] : 1.0f;
    float4 o;
    o.x = acc[i2][0] * rs; o.y = acc[i2][1] * rs; o.z = acc[i2][2] * rs; o.w = acc[i2][3] * rs;
    *(float4*)(C + (size_t)row * ldc + ccol0 + n0 + tc * 4) = o;
  }
}

// ---------------- kNN: 10 smallest d2 per row (diag excluded) --------------
__global__ __launch_bounds__(256) void k_knn(const float* __restrict__ G,
                                             const float* __restrict__ sq,
                                             int* __restrict__ top10) {
  __shared__ float sv[N2];
  __shared__ float rv[4];
  __shared__ int ri[4];
  int i = blockIdx.x, tid = threadIdx.x;
  float sqi = sq[i];
  for (int j = tid; j < N2; j += 256) {
    float d2 = sqi + sq[j] - 2.0f * G[(size_t)i * N2 + j];
    sv[j] = (j == i) ? BIGF : d2;
  }
  __syncthreads();
  for (int t = 0; t < KNN; t++) {
    float bv = BIGF;
    int bi = 1 << 30;
    for (int j = tid; j < N2; j += 256) {
      float vj = sv[j];
      if (vj < bv || (vj == bv && j < bi)) { bv = vj; bi = j; }
    }
#pragma unroll
    for (int off = 32; off; off >>= 1) {
      float ov = __shfl_down(bv, off);
      int oi = __shfl_down(bi, off);
      if (ov < bv || (ov == bv && oi < bi)) { bv = ov; bi = oi; }
    }
    if ((tid & 63) == 0) { rv[tid >> 6] = bv; ri[tid >> 6] = bi; }
    __syncthreads();
    if (tid == 0) {
      for (int wq = 1; wq < 4; wq++) {
        if (rv[wq] < bv || (rv[wq] == bv && ri[wq] < bi)) { bv = rv[wq]; bi = ri[wq]; }
      }
      top10[i * KNN + t] = bi;
      sv[bi] = BIGF;
    }
    __syncthreads();
  }
}

__global__ void k_scatter(const int* __restrict__ top10, unsigned char* __restrict__ dense) {
  int t = blockIdx.x * 256 + threadIdx.x;
  if (t >= N2 * KNN) return;
  int i = t / KNN;
  int j = top10[t];
  dense[(size_t)i * N2 + j] = 1;
  dense[(size_t)j * N2 + i] = 1;
}

__global__ __launch_bounds__(256) void k_compact(const unsigned char* __restrict__ dense,
                                                 int* __restrict__ nbr, int* __restrict__ deg,
                                                 int* __restrict__ mdeg) {
  __shared__ int cnt;
  int i = blockIdx.x, tid = threadIdx.x;
  if (tid == 0) cnt = 0;
  __syncthreads();
  for (int j = tid; j < N2; j += 256) {
    if (dense[(size_t)i * N2 + j]) {
      int p = atomicAdd(&cnt, 1);
      if (p < 64) nbr[i * 64 + p] = j;
    }
  }
  __syncthreads();
  if (tid == 0) {
    int dg = cnt > 64 ? 64 : cnt;
    deg[i] = dg;
    atomicMax(mdeg, dg);
  }
}

// ---------------- Chebyshev on (I + 0.5 L) X = B, spectrum [1, 1+maxdeg] ---
// k_cheb1: d = (k==0 ? r/theta : rho_k*rho_{k-1}*d + (2 rho_k/delta)*r); x += d
__global__ __launch_bounds__(256) void k_cheb1(float* __restrict__ d, float* __restrict__ x,
                                               const float* __restrict__ r,
                                               const int* __restrict__ mdeg, int k) {
  int idx = blockIdx.x * 256 + threadIdx.x;     // float4 index, 262144 total
  int c4 = (idx * 4) & (NCOL - 1);
  int g = c4 >> 8;
  float lmax = 1.0f + (float)mdeg[g];
  float theta = 0.5f * (lmax + 1.0f), delta = 0.5f * (lmax - 1.0f);
  float4 rr = ((const float4*)r)[idx];
  float4 xx = ((const float4*)x)[idx];
  float4 dd;
  if (k == 0) {
    float it = 1.0f / theta;
    dd.x = rr.x * it; dd.y = rr.y * it; dd.z = rr.z * it; dd.w = rr.w * it;
  } else {
    float sigma1 = theta / delta;
    float rp = delta / theta, rc = 0.0f;
    for (int t = 1; t <= k; t++) {
      rc = 1.0f / (2.0f * sigma1 - rp);
      if (t < k) rp = rc;
    }
    float ca = rc * rp, cb = 2.0f * rc / delta;
    float4 dold = ((const float4*)d)[idx];
    dd.x = ca * dold.x + cb * rr.x;
    dd.y = ca * dold.y + cb * rr.y;
    dd.z = ca * dold.z + cb * rr.z;
    dd.w = ca * dold.w + cb * rr.w;
  }
  xx.x += dd.x; xx.y += dd.y; xx.z += dd.z; xx.w += dd.w;
  ((float4*)d)[idx] = dd;
  ((float4*)x)[idx] = xx;
}

// k_cheb2: r -= (I + 0.5 L) d   (sparse, per-graph adjacency)
__global__ __launch_bounds__(256) void k_cheb2(float* __restrict__ r, const float* __restrict__ d,
                                               const int* __restrict__ nbrA, const int* __restrict__ degA,
                                               const int* __restrict__ nbrB, const int* __restrict__ degB) {
  int bx = blockIdx.x;                // 8 col-blocks of 64
  int by = blockIdx.y;                // 64 node-blocks of 32
  int tx = threadIdx.x & 63, ty = threadIdx.x >> 6;
  int c = bx * 64 + tx;
  int g = bx >> 2;
  const int* nbr = g ? nbrB : nbrA;
  const int* deg = g ? degB : degA;
  for (int s = 0; s < 8; s++) {
    int i = by * 32 + ty * 8 + s;
    int dg = deg[i];
    float di = d[(size_t)i * NCOL + c];
    float acc = (1.0f + 0.5f * (float)dg) * di;
    const int* nl = nbr + i * 64;
    for (int t = 0; t < dg; t++) {
      int j = nl[t];
      acc -= 0.5f * d[(size_t)j * NCOL + c];
    }
    r[(size_t)i * NCOL + c] -= acc;
  }
}

// ---------------- loss ----------------
__global__ __launch_bounds__(256) void k_loss(const float* __restrict__ x,
                                              const float* __restrict__ zA,
                                              const float* __restrict__ zB,
                                              float* __restrict__ part) {
  int tid0 = blockIdx.x * 256 + threadIdx.x;
  float s = 0.0f;
#pragma unroll
  for (int rep = 0; rep < 2; rep++) {
    int idx = tid0 + rep * 131072;    // float4 index
    int flat = idx * 4;
    int i = flat >> 9;
    int c = flat & (NCOL - 1);
    const float* z = (c < DDIM) ? (zA + (size_t)i * DDIM + c)
                                : (zB + (size_t)i * DDIM + (c - DDIM));
    float4 x4 = ((const float4*)x)[idx];
    float4 z4 = *(const float4*)z;
    float a = z4.x - x4.x, b = z4.y - x4.y, cc = z4.z - x4.z, dd = z4.w - x4.w;
    s += a * a + b * b + cc * cc + dd * dd;
  }
  __shared__ float red[4];
#pragma unroll
  for (int off = 32; off; off >>= 1) s += __shfl_down(s, off);
  if ((threadIdx.x & 63) == 0) red[threadIdx.x >> 6] = s;
  __syncthreads();
  if (threadIdx.x == 0) part[blockIdx.x] = red[0] + red[1] + red[2] + red[3];
}

__global__ __launch_bounds__(256) void k_final(const float* __restrict__ part,
                                               float* __restrict__ out) {
  float s = part[threadIdx.x] + part[threadIdx.x + 256];
  __shared__ float red[4];
#pragma unroll
  for (int off = 32; off; off >>= 1) s += __shfl_down(s, off);
  if ((threadIdx.x & 63) == 0) red[threadIdx.x >> 6] = s;
  __syncthreads();
  if (threadIdx.x == 0) out[0] = (red[0] + red[1] + red[2] + red[3]) * (1.0f / 524288.0f);
}

extern "C" void kernel_launch(void* const* d_in, const int* in_sizes, int n_in,
                              void* d_out, int out_size, void* d_ws, size_t ws_size,
                              hipStream_t stream) {
  const float* C  = (const float*)d_in[0];
  const float* zA = (const float*)d_in[1];
  const float* zB = (const float*)d_in[2];
  float* out = (float*)d_out;

  float* ws = (float*)d_ws;
  float* K   = ws;
  float* KT  = K  + (size_t)N2 * N2;
  float* G   = KT + (size_t)N2 * N2;
  float* r   = G  + (size_t)N2 * N2;
  float* x   = r  + (size_t)N2 * NCOL;
  float* dv  = x  + (size_t)N2 * NCOL;
  float* u   = dv + (size_t)N2 * NCOL;
  float* v   = u + N2;
  float* scA = v + N2;
  float* scB = scA + N2;
  float* sq  = scB + N2;
  float* part = sq + N2;
  int* top10 = (int*)(part + 512);
  int* nbrA  = top10 + N2 * KNN;
  int* degA  = nbrA + N2 * 64;
  int* nbrB  = degA + N2;
  int* degB  = nbrB + N2 * 64;
  int* mdeg  = degB + N2;
  unsigned char* dense = (unsigned char*)(mdeg + 64);

  // K = exp(-C/reg), KT = K^T
  k_exp_tr<<<dim3(64, 64), 256, 0, stream>>>(C, K, KT);
  k_init<<<8, 256, 0, stream>>>(u, v, mdeg);

  // unbalanced Sinkhorn, 100 iterations
  for (int it = 0; it < NIT_SINK; ++it) {
    k_sink<<<512, 256, 0, stream>>>(K, v, u);
    k_sink<<<512, 256, 0, stream>>>(KT, u, v);
  }
  // marginal scale vectors: scA = u/(u*(Kv)+eps), scB = v/(v*(KTu)+eps)
  k_scale<<<512, 256, 0, stream>>>(K, v, u, scA);
  k_scale<<<512, 256, 0, stream>>>(KT, u, v, scB);

  // barycentric projections into r (cols 0..255 graph A, 256..511 graph B)
  k_gemm<0, 1><<<dim3(4, 32), 256, 0, stream>>>(K, N2, zB, DDIM, v, scA, r, NCOL, 0, N2);
  k_gemm<0, 1><<<dim3(4, 32), 256, 0, stream>>>(KT, N2, zA, DDIM, u, scB, r, NCOL, DDIM, N2);

  // graph A: Gram -> kNN -> dense sym adjacency -> lists
  k_sq<<<512, 256, 0, stream>>>(zA, sq);
  k_gemm<1, 0><<<dim3(32, 32), 256, 0, stream>>>(zA, DDIM, zA, DDIM, nullptr, nullptr, G, N2, 0, DDIM);
  k_knn<<<2048, 256, 0, stream>>>(G, sq, top10);
  hipMemsetAsync(dense, 0, (size_t)N2 * N2, stream);
  k_scatter<<<80, 256, 0, stream>>>(top10, dense);
  k_compact<<<2048, 256, 0, stream>>>(dense, nbrA, degA, mdeg + 0);

  // graph B
  k_sq<<<512, 256, 0, stream>>>(zB, sq);
  k_gemm<1, 0><<<dim3(32, 32), 256, 0, stream>>>(zB, DDIM, zB, DDIM, nullptr, nullptr, G, N2, 0, DDIM);
  k_knn<<<2048, 256, 0, stream>>>(G, sq, top10);
  hipMemsetAsync(dense, 0, (size_t)N2 * N2, stream);
  k_scatter<<<80, 256, 0, stream>>>(top10, dense);
  k_compact<<<2048, 256, 0, stream>>>(dense, nbrB, degB, mdeg + 1);

  // Chebyshev solve (I + 0.5 L)^{-1} r  -> x  (both graphs batched, 512 cols)
  hipMemsetAsync(x, 0, (size_t)N2 * NCOL * sizeof(float), stream);
  for (int k = 0; k < NIT_CHEB; k++) {
    k_cheb1<<<1024, 256, 0, stream>>>(dv, x, r, mdeg, k);
    if (k < NIT_CHEB - 1)
      k_cheb2<<<dim3(8, 64), 256, 0, stream>>>(r, dv, nbrA, degA, nbrB, degB);
  }

  // loss = mean((zA-xA)^2) + mean((zB-xB)^2)
  k_loss<<<512, 256, 0, stream>>>(x, zA, zB, part);
  k_final<<<1, 256, 0, stream>>>(part, out);
}